// Round 1
// baseline (169.634 us; speedup 1.0000x reference)
//
#include <hip/hip_runtime.h>

#define BB 4
#define TQ 512
#define TK 512
#define DQ 512
#define UU 256
#define CSC 2.8853900817779268f   // 2*log2(e): folded into projections so x = 2*log2e*(q+k)
#define L2E 1.4426950408889634f

__device__ __forceinline__ float fexp2(float x) { return __builtin_amdgcn_exp2f(x); }
__device__ __forceinline__ float frcp(float x)  { return __builtin_amdgcn_rcpf(x); }

// C = CSC * (A @ W);  A:[M,K] row-major, W:[K,N] row-major, C:[M,N]
// M = BB*512 = 2048, K = 512, N = 256. blockIdx.z selects (query,W1)->Cq vs (value,W2)->Ck.
__global__ __launch_bounds__(256) void gemm_both(
    const float* __restrict__ Aq, const float* __restrict__ Av,
    const float* __restrict__ W1, const float* __restrict__ W2,
    float* __restrict__ Cq, float* __restrict__ Ck)
{
    const int K = DQ, N = UU;
    const float* A; const float* W; float* C;
    if (blockIdx.z == 0) { A = Aq; W = W1; C = Cq; }
    else                 { A = Av; W = W2; C = Ck; }

    __shared__ float As[16][68];   // As[kk][mm], padded row stride 68 (16B-aligned rows)
    __shared__ float Ws[16][68];   // Ws[kk][nn]

    const int tid = threadIdx.x;
    const int m0 = blockIdx.x * 64;
    const int n0 = blockIdx.y * 64;
    const int tm = (tid >> 4) << 2;     // 0..60
    const int tn = (tid & 15) << 2;     // 0..60
    // A-tile load mapping: 64 rows x 16 k, float4 along k
    const int a_mm = tid >> 2;          // 0..63
    const int a_kk = (tid & 3) << 2;    // 0,4,8,12
    // W-tile load mapping: 16 k x 64 n, float4 along n
    const int w_kk = tid >> 4;          // 0..15
    const int w_nn = (tid & 15) << 2;   // 0..60

    float acc[4][4] = {};

    for (int k0 = 0; k0 < K; k0 += 16) {
        const float4 av = *(const float4*)&A[(size_t)(m0 + a_mm) * K + k0 + a_kk];
        const float4 wv = *(const float4*)&W[(size_t)(k0 + w_kk) * N + n0 + w_nn];
        __syncthreads();   // previous iteration's compute reads done before overwrite
        As[a_kk + 0][a_mm] = av.x;
        As[a_kk + 1][a_mm] = av.y;
        As[a_kk + 2][a_mm] = av.z;
        As[a_kk + 3][a_mm] = av.w;
        *(float4*)&Ws[w_kk][w_nn] = wv;
        __syncthreads();
        #pragma unroll
        for (int kk = 0; kk < 16; kk++) {
            const float4 a4 = *(const float4*)&As[kk][tm];
            const float4 w4 = *(const float4*)&Ws[kk][tn];
            const float aa[4] = {a4.x, a4.y, a4.z, a4.w};
            const float ww[4] = {w4.x, w4.y, w4.z, w4.w};
            #pragma unroll
            for (int i = 0; i < 4; i++)
                #pragma unroll
                for (int j = 0; j < 4; j++)
                    acc[i][j] = fmaf(aa[i], ww[j], acc[i][j]);
        }
    }
    #pragma unroll
    for (int i = 0; i < 4; i++) {
        float4 o = make_float4(CSC * acc[i][0], CSC * acc[i][1],
                               CSC * acc[i][2], CSC * acc[i][3]);
        *(float4*)&C[(size_t)(m0 + tm + i) * N + n0 + tn] = o;
    }
}

// kT[b][u][j] = kp[b][j][u]
__global__ __launch_bounds__(256) void transpose_k(
    const float* __restrict__ kp, float* __restrict__ kT)
{
    __shared__ float tile[32][33];
    const int b  = blockIdx.z;
    const int j0 = blockIdx.x * 32;
    const int u0 = blockIdx.y * 32;
    const int tx = threadIdx.x;   // 0..31
    const int ty = threadIdx.y;   // 0..7
    #pragma unroll
    for (int r = 0; r < 32; r += 8)
        tile[ty + r][tx] = kp[(size_t)(b * TK + j0 + ty + r) * UU + u0 + tx];
    __syncthreads();
    #pragma unroll
    for (int r = 0; r < 32; r += 8)
        kT[(size_t)(b * UU + u0 + ty + r) * TK + j0 + tx] = tile[tx][ty + r];
}

// One block per (b, 8 q-rows); 512 threads, thread t = column j.
// scores[r][t] = sum_scale + sum_u (-2*scale_u) / (1 + 2^(qs[r][u] + kT[u][t]))
// then row-wise softmax over t, coalesced store.
__global__ __launch_bounds__(512) void attn_softmax(
    const float* __restrict__ qp,   // [BB, TQ, UU], pre-scaled by 2log2e
    const float* __restrict__ kT,   // [BB, UU, TK], pre-scaled by 2log2e
    const float* __restrict__ scale,// [UU]
    float* __restrict__ out)        // [BB, TQ, TK]
{
    __shared__ float qs[8][UU];     // 8 KB
    __shared__ float cs[UU];        // -2*scale[u]
    __shared__ float redbuf[8][8];  // [row][wave]

    const int t  = threadIdx.x;
    const int b  = blockIdx.x >> 6;         // TQ/8 = 64 blocks per b
    const int q0 = (blockIdx.x & 63) << 3;

    for (int i = t; i < 8 * UU; i += 512) {
        const int r = i >> 8, u = i & (UU - 1);
        qs[r][u] = qp[(size_t)(b * TQ + q0 + r) * UU + u];
    }
    if (t < UU) cs[t] = -2.0f * scale[t];
    __syncthreads();

    float sscale = 0.0f;
    for (int u = 0; u < UU; u++) sscale += cs[u];
    sscale *= -0.5f;                 // = sum_u scale[u]

    float acc[8] = {0, 0, 0, 0, 0, 0, 0, 0};
    const float* kb = kT + (size_t)b * UU * TK + t;
    #pragma unroll 2
    for (int u = 0; u < UU; u++) {
        const float kv = kb[(size_t)u * TK];   // coalesced across threads
        const float c  = cs[u];
        #pragma unroll
        for (int r = 0; r < 8; r++) {
            const float x  = qs[r][u] + kv;    // = 2log2e*(q+k)
            const float e  = fexp2(x);
            const float rr = frcp(1.0f + e);
            acc[r] = fmaf(c, rr, acc[r]);      // += -2*scale_u/(1+e^{2y})
        }
    }

    const int wave = t >> 6, lane = t & 63;
    float s[8], m[8], p[8];
    #pragma unroll
    for (int r = 0; r < 8; r++) s[r] = sscale + acc[r];

    // row max over 512 threads
    #pragma unroll
    for (int r = 0; r < 8; r++) {
        float v = s[r];
        #pragma unroll
        for (int o = 32; o > 0; o >>= 1) v = fmaxf(v, __shfl_xor(v, o));
        if (lane == 0) redbuf[r][wave] = v;
    }
    __syncthreads();
    #pragma unroll
    for (int r = 0; r < 8; r++) {
        float v = redbuf[r][0];
        #pragma unroll
        for (int w = 1; w < 8; w++) v = fmaxf(v, redbuf[r][w]);
        m[r] = v;
    }
    __syncthreads();

    // exp and row sum
    #pragma unroll
    for (int r = 0; r < 8; r++) {
        p[r] = fexp2(L2E * (s[r] - m[r]));
        float v = p[r];
        #pragma unroll
        for (int o = 32; o > 0; o >>= 1) v += __shfl_xor(v, o);
        if (lane == 0) redbuf[r][wave] = v;
    }
    __syncthreads();
    #pragma unroll
    for (int r = 0; r < 8; r++) {
        float v = 0.0f;
        #pragma unroll
        for (int w = 0; w < 8; w++) v += redbuf[r][w];
        const float rinv = frcp(v);
        out[(size_t)(b * TQ + q0 + r) * TK + t] = p[r] * rinv;
    }
}

extern "C" void kernel_launch(void* const* d_in, const int* in_sizes, int n_in,
                              void* d_out, int out_size, void* d_ws, size_t ws_size,
                              hipStream_t stream) {
    const float* query = (const float*)d_in[0];
    const float* value = (const float*)d_in[1];
    const float* W1    = (const float*)d_in[2];
    const float* W2    = (const float*)d_in[3];
    const float* scale = (const float*)d_in[4];
    float* out = (float*)d_out;

    float* qp = (float*)d_ws;                     // [BB,TQ,UU]  2 MB
    float* kp = qp + (size_t)BB * TQ * UU;        // [BB,TK,UU]  2 MB
    float* kT = kp + (size_t)BB * TK * UU;        // [BB,UU,TK]  2 MB

    gemm_both<<<dim3(32, 4, 2), 256, 0, stream>>>(query, value, W1, W2, qp, kp);
    transpose_k<<<dim3(TK / 32, UU / 32, BB), dim3(32, 8), 0, stream>>>(kp, kT);
    attn_softmax<<<dim3(BB * TQ / 8), 512, 0, stream>>>(qp, kT, scale, out);
}